// Round 1
// baseline (1672.632 us; speedup 1.0000x reference)
//
#include <hip/hip_runtime.h>
#include <math.h>

#define N_TOK 2048
#define NH 8
#define DH 40

// ---------------- generic tiled fp32 GEMM: C = A(MxK)*B(KxN) + bias, optional relu
// 64x64 tile, 16x16 threads, 4x4 per thread. M,K multiples of 16/64; N guarded.
__global__ __launch_bounds__(256) void gemm_k(const float* __restrict__ A,
    const float* __restrict__ B, const float* __restrict__ bias,
    float* __restrict__ C, int M, int N, int K, int relu)
{
    __shared__ float As[16][65];
    __shared__ float Bs[16][65];
    const int bn = blockIdx.x * 64, bm = blockIdx.y * 64;
    const int tx = threadIdx.x, ty = threadIdx.y;
    const int tid = ty * 16 + tx;
    float acc[4][4] = {};
    for (int k0 = 0; k0 < K; k0 += 16) {
        {
            const int kk = tid & 15, mm = tid >> 4;
            #pragma unroll
            for (int l = 0; l < 4; ++l)
                As[kk][mm + 16 * l] = A[(bm + mm + 16 * l) * K + k0 + kk];
        }
        {
            const int nn = tid & 63, kb = tid >> 6;
            #pragma unroll
            for (int l = 0; l < 4; ++l) {
                const int kk = kb + 4 * l;
                const int ng = bn + nn;
                Bs[kk][nn] = (ng < N) ? B[(k0 + kk) * N + ng] : 0.0f;
            }
        }
        __syncthreads();
        #pragma unroll
        for (int kk = 0; kk < 16; ++kk) {
            float a0 = As[kk][ty], a1 = As[kk][ty + 16], a2 = As[kk][ty + 32], a3 = As[kk][ty + 48];
            float b0 = Bs[kk][tx], b1 = Bs[kk][tx + 16], b2 = Bs[kk][tx + 32], b3 = Bs[kk][tx + 48];
            acc[0][0] += a0 * b0; acc[0][1] += a0 * b1; acc[0][2] += a0 * b2; acc[0][3] += a0 * b3;
            acc[1][0] += a1 * b0; acc[1][1] += a1 * b1; acc[1][2] += a1 * b2; acc[1][3] += a1 * b3;
            acc[2][0] += a2 * b0; acc[2][1] += a2 * b1; acc[2][2] += a2 * b2; acc[2][3] += a2 * b3;
            acc[3][0] += a3 * b0; acc[3][1] += a3 * b1; acc[3][2] += a3 * b2; acc[3][3] += a3 * b3;
        }
        __syncthreads();
    }
    #pragma unroll
    for (int i = 0; i < 4; ++i) {
        const int row = bm + ty + 16 * i;
        #pragma unroll
        for (int j = 0; j < 4; ++j) {
            const int col = bn + tx + 16 * j;
            if (col < N) {
                float v = acc[i][j] + bias[col];
                if (relu) v = fmaxf(v, 0.0f);
                C[row * N + col] = v;
            }
        }
    }
}

// ---------------- tiny-N linear: out[i,n] = sum_k A[i,k]*W[k,n] + b[n]
__global__ void rowdot_k(const float* __restrict__ A, const float* __restrict__ W,
                         const float* __restrict__ bias, float* __restrict__ out,
                         int K, int N)
{
    const int t = blockIdx.x * blockDim.x + threadIdx.x;
    if (t >= N_TOK * N) return;
    const int i = t / N, n = t % N;
    float acc = 0.0f;
    for (int k = 0; k < K; ++k) acc += A[i * K + k] * W[k * N + n];
    out[t] = acc + bias[n];
}

// ---------------- flash attention, fp32, 8 heads, DH=40, from packed qkv (N,960)
// block: 16 q-rows x 256 threads (16 threads per q-row); kv tiles of 64
#define TKV 64
#define QR 16
__global__ __launch_bounds__(256) void attn_k(const float* __restrict__ qkv,
                                              float* __restrict__ ctxo)
{
    __shared__ float Qs[QR][41];
    __shared__ float Ks[TKV][41];
    __shared__ float Vs[TKV][41];
    const int h = blockIdx.y;
    const int q0 = blockIdx.x * QR;
    const int tid = threadIdx.x;
    const int qr = tid >> 4, kc = tid & 15;
    for (int idx = tid; idx < QR * DH; idx += 256) {
        const int r = idx / DH, d = idx % DH;
        Qs[r][d] = qkv[(q0 + r) * 960 + h * DH + d];
    }
    float M = -1e30f, S = 0.0f;
    float ctx[DH];
    #pragma unroll
    for (int d = 0; d < DH; ++d) ctx[d] = 0.0f;
    const float scale = 0.15811388300841897f; // 1/sqrt(40)

    for (int t0 = 0; t0 < N_TOK; t0 += TKV) {
        __syncthreads();
        for (int idx = tid; idx < TKV * DH; idx += 256) {
            const int r = idx / DH, d = idx % DH;
            Ks[r][d] = qkv[(t0 + r) * 960 + 320 + h * DH + d];
            Vs[r][d] = qkv[(t0 + r) * 960 + 640 + h * DH + d];
        }
        __syncthreads();
        float s[4];
        #pragma unroll
        for (int u = 0; u < 4; ++u) {
            const int kl = kc + 16 * u;
            float acc = 0.0f;
            #pragma unroll
            for (int d = 0; d < DH; ++d) acc += Qs[qr][d] * Ks[kl][d];
            s[u] = acc * scale;
        }
        float tmax = fmaxf(fmaxf(s[0], s[1]), fmaxf(s[2], s[3]));
        #pragma unroll
        for (int off = 1; off < 16; off <<= 1) tmax = fmaxf(tmax, __shfl_xor(tmax, off, 16));
        const float Mnew = fmaxf(M, tmax);
        const float sc = expf(M - Mnew);
        float p[4], ps = 0.0f;
        #pragma unroll
        for (int u = 0; u < 4; ++u) { p[u] = expf(s[u] - Mnew); ps += p[u]; }
        #pragma unroll
        for (int off = 1; off < 16; off <<= 1) ps += __shfl_xor(ps, off, 16);
        S = S * sc + ps;
        #pragma unroll
        for (int d = 0; d < DH; ++d) {
            float a = ctx[d] * sc;
            #pragma unroll
            for (int u = 0; u < 4; ++u) a += p[u] * Vs[kc + 16 * u][d];
            ctx[d] = a;
        }
        M = Mnew;
    }
    #pragma unroll
    for (int off = 1; off < 16; off <<= 1) {
        #pragma unroll
        for (int d = 0; d < DH; ++d) ctx[d] += __shfl_xor(ctx[d], off, 16);
    }
    const float rS = 1.0f / S;
    const int q = q0 + qr;
    for (int d = kc; d < DH; d += 16)
        ctxo[q * 320 + h * DH + d] = ctx[d] * rS;
}

// ---------------- refinement: one Adam step. 256 blocks x 256 threads, 8 rows/block.
#define RPB 8
__global__ __launch_bounds__(256) void refine_k(const float* __restrict__ xin,
    float* __restrict__ xout, float* __restrict__ mbuf, float* __restrict__ vbuf,
    const float* __restrict__ prob, float bc1, float bc2)
{
    __shared__ float xs[N_TOK * 3];
    __shared__ float cs[N_TOK];
    const int tid = threadIdx.x;
    for (int idx = tid; idx < N_TOK * 3; idx += 256) xs[idx] = xin[idx];
    for (int idx = tid; idx < N_TOK; idx += 256) cs[idx] = prob[idx];
    __syncthreads();
    const int r = tid >> 5, lane = tid & 31;
    const int i = blockIdx.x * RPB + r;
    const float xi0 = xs[i * 3], xi1 = xs[i * 3 + 1], xi2 = xs[i * 3 + 2];
    const float ci = cs[i];
    float g0 = 0.0f, g1 = 0.0f, g2 = 0.0f;
    #pragma unroll 4
    for (int u = 0; u < N_TOK / 32; ++u) {
        const int j = lane + 32 * u;
        const float dx = xi0 - xs[j * 3];
        const float dy = xi1 - xs[j * 3 + 1];
        const float dz = xi2 - xs[j * 3 + 2];
        const float d2 = dx * dx + dy * dy + dz * dz + 1e-12f;
        const float rinv = rsqrtf(d2);
        const float d = d2 * rinv;
        const float sc = ci + cs[j];
        float w = 0.0f;
        if (d > 8.0f)  w += sc;
        if (d < 12.0f) w -= (2.0f - sc);
        const float f = w * rinv;
        g0 += f * dx; g1 += f * dy; g2 += f * dz;
    }
    #pragma unroll
    for (int off = 16; off > 0; off >>= 1) {
        g0 += __shfl_xor(g0, off, 32);
        g1 += __shfl_xor(g1, off, 32);
        g2 += __shfl_xor(g2, off, 32);
    }
    if (lane == 0) {
        const float gs = 1.0f / ((float)N_TOK * (float)N_TOK);
        g0 *= gs; g1 *= gs; g2 *= gs;
        const float bw = 0.1f / (float)(N_TOK - 1);
        if (i > 0) {
            const float dx = xi0 - xs[(i - 1) * 3];
            const float dy = xi1 - xs[(i - 1) * 3 + 1];
            const float dz = xi2 - xs[(i - 1) * 3 + 2];
            const float b2 = dx * dx + dy * dy + dz * dz + 1e-12f;
            const float rb = rsqrtf(b2);
            if (b2 * rb > 4.0f) { const float f = bw * rb; g0 += f * dx; g1 += f * dy; g2 += f * dz; }
        }
        if (i < N_TOK - 1) {
            const float dx = xi0 - xs[(i + 1) * 3];
            const float dy = xi1 - xs[(i + 1) * 3 + 1];
            const float dz = xi2 - xs[(i + 1) * 3 + 2];
            const float b2 = dx * dx + dy * dy + dz * dz + 1e-12f;
            const float rb = rsqrtf(b2);
            if (b2 * rb > 4.0f) { const float f = bw * rb; g0 += f * dx; g1 += f * dy; g2 += f * dz; }
        }
        const float g[3] = { g0, g1, g2 };
        #pragma unroll
        for (int c = 0; c < 3; ++c) {
            const int idx = i * 3 + c;
            const float mm = 0.9f * mbuf[idx] + 0.1f * g[c];
            const float vv = 0.999f * vbuf[idx] + 0.001f * g[c] * g[c];
            mbuf[idx] = mm; vbuf[idx] = vv;
            const float mh = mm / bc1;
            const float vh = vv / bc2;
            xout[idx] = xs[idx] - 0.01f * mh / (sqrtf(vh) + 1e-8f);
        }
    }
}

__global__ void init_k(const float* __restrict__ s0, float* __restrict__ xA,
                       float* __restrict__ m, float* __restrict__ v)
{
    const int t = blockIdx.x * 256 + threadIdx.x;
    if (t < N_TOK * 3) { xA[t] = s0[t]; m[t] = 0.0f; v[t] = 0.0f; }
}

__global__ void copy_k(const float* __restrict__ src, float* __restrict__ dst)
{
    const int t = blockIdx.x * 256 + threadIdx.x;
    if (t < N_TOK * 3) dst[t] = src[t];
}

extern "C" void kernel_launch(void* const* d_in, const int* in_sizes, int n_in,
                              void* d_out, int out_size, void* d_ws, size_t ws_size,
                              hipStream_t stream)
{
    (void)in_sizes; (void)n_in; (void)out_size; (void)ws_size;
    const float* F    = (const float*)d_in[0];
    const float* bbw1 = (const float*)d_in[1];  const float* bbb1 = (const float*)d_in[2];
    const float* bbw2 = (const float*)d_in[3];  const float* bbb2 = (const float*)d_in[4];
    const float* wqkv = (const float*)d_in[9];  const float* bqkv = (const float*)d_in[10];
    const float* wo   = (const float*)d_in[11]; const float* bo   = (const float*)d_in[12];
    const float* cmw1 = (const float*)d_in[13]; const float* cmb1 = (const float*)d_in[14];
    const float* cmw2 = (const float*)d_in[15]; const float* cmb2 = (const float*)d_in[16];
    const float* rbw1 = (const float*)d_in[17]; const float* rbb1 = (const float*)d_in[18];
    const float* rbw2 = (const float*)d_in[19]; const float* rbb2 = (const float*)d_in[20];

    float* ws   = (float*)d_ws;
    float* h1   = ws;               // 2048*320
    float* bf   = h1 + 655360;      // 2048*320
    float* qkv  = bf + 655360;      // 2048*960
    float* t1   = qkv + 1966080;    // 2048*160
    float* ctxo = t1 + 327680;      // 2048*320
    float* attn = ctxo + 655360;    // 2048*320
    float* c1   = attn + 655360;    // 2048*160
    float* prob = c1 + 327680;      // 2048
    float* s0   = prob + 2048;      // 6144
    float* xA   = s0 + 6144;
    float* xB   = xA + 6144;
    float* mb   = xB + 6144;
    float* vb   = mb + 6144;

    const dim3 blk(16, 16);
    gemm_k<<<dim3(5, 32),  blk, 0, stream>>>(F,    bbw1, bbb1, h1,   2048, 320, 320, 1);
    gemm_k<<<dim3(5, 32),  blk, 0, stream>>>(h1,   bbw2, bbb2, bf,   2048, 320, 320, 0);
    gemm_k<<<dim3(15, 32), blk, 0, stream>>>(F,    wqkv, bqkv, qkv,  2048, 960, 320, 0);
    gemm_k<<<dim3(3, 32),  blk, 0, stream>>>(bf,   rbw1, rbb1, t1,   2048, 160, 320, 1);
    rowdot_k<<<(N_TOK * 3 + 255) / 256, 256, 0, stream>>>(t1, rbw2, rbb2, s0, 160, 3);
    attn_k<<<dim3(N_TOK / QR, NH), 256, 0, stream>>>(qkv, ctxo);
    gemm_k<<<dim3(5, 32),  blk, 0, stream>>>(ctxo, wo,   bo,   attn, 2048, 320, 320, 0);
    gemm_k<<<dim3(3, 32),  blk, 0, stream>>>(attn, cmw1, cmb1, c1,   2048, 160, 320, 1);
    rowdot_k<<<(N_TOK + 255) / 256, 256, 0, stream>>>(c1, cmw2, cmb2, prob, 160, 1);
    init_k<<<24, 256, 0, stream>>>(s0, xA, mb, vb);

    float* cur = xA; float* nxt = xB;
    for (int t = 1; t <= 100; ++t) {
        const float bc1 = (float)(1.0 - pow(0.9,   (double)t));
        const float bc2 = (float)(1.0 - pow(0.999, (double)t));
        refine_k<<<N_TOK / RPB, 256, 0, stream>>>(cur, nxt, mb, vb, prob, bc1, bc2);
        float* tmp = cur; cur = nxt; nxt = tmp;
    }
    copy_k<<<24, 256, 0, stream>>>(cur, (float*)d_out);
}